// Round 4
// baseline (545.988 us; speedup 1.0000x reference)
//
#include <hip/hip_runtime.h>
#include <cstdint>
#include <cstddef>

#define D_MODEL 2048
#define T_SEQ   2048
#define BATCH   2
#define N_HEADS 16
#define KV_HEADS 4
#define HEAD_DIM 128
#define QKV_N   3072          // D_MODEL + 2*512
#define ROWS    (BATCH * T_SEQ) // 4096

typedef float  floatx4 __attribute__((ext_vector_type(4)));
typedef short  shortx8 __attribute__((ext_vector_type(8)));
typedef __bf16 bf16x8  __attribute__((ext_vector_type(8)));

typedef const void __attribute__((address_space(1))) gvoid_t;
typedef void __attribute__((address_space(3)))       svoid_t;

__device__ __forceinline__ floatx4 mfma16(shortx8 a, shortx8 b, floatx4 c) {
  return __builtin_amdgcn_mfma_f32_16x16x32_bf16(
      __builtin_bit_cast(bf16x8, a), __builtin_bit_cast(bf16x8, b), c, 0, 0, 0);
}

__device__ __forceinline__ unsigned short f2bf(float f) {
  union { float f; unsigned int u; } v; v.f = f;
  unsigned int u = v.u;
  u += 0x7fffu + ((u >> 16) & 1u);   // RNE
  return (unsigned short)(u >> 16);
}

// memory-clobbered raw barrier (no vmcnt(0) drain, unlike __syncthreads)
#define RAW_BARRIER() do { \
  __asm__ __volatile__("" ::: "memory"); \
  __builtin_amdgcn_s_barrier(); \
  __asm__ __volatile__("" ::: "memory"); \
} while (0)

// ---------------- fp32 -> bf16 elementwise (x) ----------------
__global__ void cvt_x(const float* __restrict__ in, unsigned short* __restrict__ out, int n4) {
  int i = blockIdx.x * blockDim.x + threadIdx.x;
  if (i >= n4) return;
  float4 v = ((const float4*)in)[i];
  ushort4 o;
  o.x = f2bf(v.x); o.y = f2bf(v.y); o.z = f2bf(v.z); o.w = f2bf(v.w);
  ((ushort4*)out)[i] = o;
}

// ---------------- fp32 W[K][N] -> bf16 Wt[N][K] ----------------
__global__ void transpose_cvt(const float* __restrict__ W, unsigned short* __restrict__ Wt,
                              int K, int N) {
  __shared__ float tile[32][33];
  int n0 = blockIdx.x * 32, k0 = blockIdx.y * 32;
  int tx = threadIdx.x, ty = threadIdx.y;   // (32, 8)
  #pragma unroll
  for (int i = 0; i < 32; i += 8)
    tile[ty + i][tx] = W[(size_t)(k0 + ty + i) * N + n0 + tx];
  __syncthreads();
  #pragma unroll
  for (int i = 0; i < 32; i += 8)
    Wt[(size_t)(n0 + ty + i) * K + k0 + tx] = f2bf(tile[tx][ty + i]);
}

// ---------------- bf16 V slice of qkv -> Vt (B,KVH,HEAD_DIM,T) ----------------
__global__ void build_vt(const unsigned short* __restrict__ qkv, unsigned short* __restrict__ vt) {
  __shared__ unsigned short tile[32][33];
  int t0  = blockIdx.x * 32;
  int d0  = (blockIdx.y & 3) * 32;
  int kvh = blockIdx.y >> 2;
  int b   = blockIdx.z;
  int tx = threadIdx.x, ty = threadIdx.y;   // (32, 8)
  #pragma unroll
  for (int i = 0; i < 32; i += 8)
    tile[ty + i][tx] = qkv[(size_t)(b * T_SEQ + t0 + ty + i) * QKV_N
                           + D_MODEL + 512 + kvh * HEAD_DIM + d0 + tx];
  __syncthreads();
  #pragma unroll
  for (int i = 0; i < 32; i += 8)
    vt[((size_t)(b * KV_HEADS + kvh) * HEAD_DIM + d0 + ty + i) * T_SEQ + t0 + tx]
        = tile[tx][ty + i];
}

// ---------------- bf16 GEMM: C[M][N] = A[M][K] * Bt[N][K]^T + bias ----------------
__global__ __launch_bounds__(256) void gemm_bt(
    const unsigned short* __restrict__ A,
    const unsigned short* __restrict__ Bt,
    const float* __restrict__ bias,
    void* __restrict__ Cout,
    int M, int N, int K, int c_bf16)
{
  __shared__ __align__(16) unsigned short sA[4 * 128 * 8];
  __shared__ __align__(16) unsigned short sB[4 * 128 * 8];
  const int tid  = threadIdx.x;
  const int wave = tid >> 6, lane = tid & 63;
  const int quad = lane >> 4, l16 = lane & 15;
  const int bm = blockIdx.y * 128, bn = blockIdx.x * 128;
  const int wm = (wave >> 1) * 64, wn = (wave & 1) * 64;
  floatx4 acc[4][4] = {};

  const int idx0 = tid, idx1 = 256 + tid;
  const int k8_0 = idx0 >> 7, r_0 = idx0 & 127;
  const int k8_1 = idx1 >> 7, r_1 = idx1 & 127;
  const unsigned short* a0 = A  + (size_t)(bm + r_0) * K + k8_0 * 8;
  const unsigned short* a1 = A  + (size_t)(bm + r_1) * K + k8_1 * 8;
  const unsigned short* b0 = Bt + (size_t)(bn + r_0) * K + k8_0 * 8;
  const unsigned short* b1 = Bt + (size_t)(bn + r_1) * K + k8_1 * 8;
  unsigned short* ldsA0 = &sA[(0 * 256 + wave * 64) * 8];
  unsigned short* ldsA1 = &sA[(1 * 256 + wave * 64) * 8];
  unsigned short* ldsB0 = &sB[(0 * 256 + wave * 64) * 8];
  unsigned short* ldsB1 = &sB[(1 * 256 + wave * 64) * 8];

  for (int k0 = 0; k0 < K; k0 += 32) {
    __syncthreads();
    __builtin_amdgcn_global_load_lds((gvoid_t*)(a0 + k0), (svoid_t*)ldsA0, 16, 0, 0);
    __builtin_amdgcn_global_load_lds((gvoid_t*)(a1 + k0), (svoid_t*)ldsA1, 16, 0, 0);
    __builtin_amdgcn_global_load_lds((gvoid_t*)(b0 + k0), (svoid_t*)ldsB0, 16, 0, 0);
    __builtin_amdgcn_global_load_lds((gvoid_t*)(b1 + k0), (svoid_t*)ldsB1, 16, 0, 0);
    __syncthreads();

    shortx8 af[4], bfq[4];
    #pragma unroll
    for (int mi = 0; mi < 4; ++mi)
      af[mi] = *(const shortx8*)&sA[(quad * 128 + wm + mi * 16 + l16) * 8];
    #pragma unroll
    for (int ni = 0; ni < 4; ++ni)
      bfq[ni] = *(const shortx8*)&sB[(quad * 128 + wn + ni * 16 + l16) * 8];
    #pragma unroll
    for (int mi = 0; mi < 4; ++mi)
      #pragma unroll
      for (int ni = 0; ni < 4; ++ni)
        acc[mi][ni] = mfma16(af[mi], bfq[ni], acc[mi][ni]);
  }

  #pragma unroll
  for (int mi = 0; mi < 4; ++mi) {
    #pragma unroll
    for (int ni = 0; ni < 4; ++ni) {
      const int row = bm + wm + mi * 16 + quad * 4;
      const int col = bn + wn + ni * 16 + l16;
      const float bv = bias[col];
      #pragma unroll
      for (int r = 0; r < 4; ++r) {
        float v = acc[mi][ni][r] + bv;
        if (c_bf16)
          ((unsigned short*)Cout)[(size_t)(row + r) * N + col] = f2bf(v);
        else
          ((float*)Cout)[(size_t)(row + r) * N + col] = v;
      }
    }
  }
}

// ---------------- flash attention, GQA, causal — software-pipelined ----------------
// grid (T/64, N_HEADS, B), block 256 (4 waves x 16 Q-rows), 64-key tiles.
// K: double-buffered global_load_lds, issued 1 iteration ahead.
// V: coalesced global->VGPR loads issued 1 iteration ahead, ds_write to padded [d][72].
// Raw s_barrier + manual vmcnt: no synchronous load drain on the critical path.
__global__ __launch_bounds__(256) void attn_kernel(
    const unsigned short* __restrict__ qkv,   // (B*T, 3072) bf16
    const unsigned short* __restrict__ vt,    // (B,KVH,HEAD_DIM,T) bf16
    unsigned short* __restrict__ aout)        // (B*T, D_MODEL) bf16
{
  __shared__ __align__(16) unsigned short sK[2][16 * 64 * 8]; // dbuf [k8][row][8]
  __shared__ __align__(16) unsigned short sV[128 * 72];       // [d][72] padded
  __shared__ __align__(16) unsigned short sP[4][8 * 16 * 8];  // per-wave [k8][row][8]

  const int tid  = threadIdx.x;
  const int wave = tid >> 6, lane = tid & 63;
  const int quad = lane >> 4, l16 = lane & 15;
  const int qt = (T_SEQ / 64 - 1) - blockIdx.x;   // long blocks first
  const int head = blockIdx.y, b = blockIdx.z;
  const int kvh = head >> 2;
  const int q0 = qt * 64;
  const float cf = 0.08838834764831845f * 1.4426950408889634f;  // scale*log2e

  // Q fragments straight to registers (A-layout: row=l16, k=ks*32+quad*8)
  shortx8 qf[4];
  {
    const unsigned short* qp = qkv + (size_t)(b * T_SEQ + q0 + wave * 16 + l16) * QKV_N
                               + head * HEAD_DIM + quad * 8;
    #pragma unroll
    for (int ks = 0; ks < 4; ++ks)
      qf[ks] = *(const shortx8*)(qp + ks * 32);
  }

  // K staging (global_load_lds): chunk it -> k8 = it*4+wave, row = lane
  const unsigned short* kgl = qkv + (size_t)(b * T_SEQ + lane) * QKV_N
                              + D_MODEL + kvh * HEAD_DIM + wave * 8;
  // V staging (coalesced): chunk it -> d = it*32 + (tid>>3), t8 = tid&7
  const int vd = tid >> 3, vt8 = tid & 7;
  const unsigned short* vglb = vt + (size_t)(b * KV_HEADS + kvh) * HEAD_DIM * T_SEQ + vt8 * 8;
  unsigned short* sPw = sP[wave];

  float m_i[4], l_i[4];
  #pragma unroll
  for (int r = 0; r < 4; ++r) { m_i[r] = -__builtin_inff(); l_i[r] = 0.f; }
  floatx4 o_acc[8] = {};

  uint4 vreg[4];

  // ---- prologue: issue tile 0 (K -> LDS buf0, V -> VGPRs) ----
  {
    unsigned short* dst = &sK[0][wave * 512];
    #pragma unroll
    for (int it = 0; it < 4; ++it)
      __builtin_amdgcn_global_load_lds((gvoid_t*)(kgl + it * 32),
                                       (svoid_t*)(dst + it * 2048), 16, 0, 0);
    #pragma unroll
    for (int it = 0; it < 4; ++it)
      vreg[it] = *(const uint4*)(vglb + (size_t)(it * 32 + vd) * T_SEQ);
  }

  for (int kt = 0; kt <= qt; ++kt) {
    const int kb = kt * 64;
    const int cur = kt & 1;

    RAW_BARRIER();   // A: all waves finished reading sV / sK[cur^1] of prev iter

    // issue K for tile kt+1 into the other buffer
    if (kt < qt) {
      const unsigned short* g = kgl + (size_t)(kb + 64) * QKV_N;
      unsigned short* dst = &sK[cur ^ 1][wave * 512];
      #pragma unroll
      for (int it = 0; it < 4; ++it)
        __builtin_amdgcn_global_load_lds((gvoid_t*)(g + it * 32),
                                         (svoid_t*)(dst + it * 2048), 16, 0, 0);
    }
    // write V tile kt (loaded last iteration) into sV
    #pragma unroll
    for (int it = 0; it < 4; ++it)
      *(uint4*)&sV[(it * 32 + vd) * 72 + vt8 * 8] = vreg[it];
    // issue V loads for tile kt+1
    if (kt < qt) {
      #pragma unroll
      for (int it = 0; it < 4; ++it)
        vreg[it] = *(const uint4*)(vglb + (size_t)(it * 32 + vd) * T_SEQ + kb + 64);
    }

    // wait: K(kt) landed (8 newer ops outstanding when pipelined), V-writes drained
    if (kt < qt) __asm__ __volatile__("s_waitcnt vmcnt(8) lgkmcnt(0)" ::: "memory");
    else         __asm__ __volatile__("s_waitcnt vmcnt(0) lgkmcnt(0)" ::: "memory");
    __builtin_amdgcn_s_barrier();   // B: tile kt fully visible
    __asm__ __volatile__("" ::: "memory");

    // S = Q K^T for this wave's 16 rows x 64 keys
    floatx4 s[4] = {};
    #pragma unroll
    for (int ks = 0; ks < 4; ++ks) {
      #pragma unroll
      for (int ct = 0; ct < 4; ++ct) {
        shortx8 kf = *(const shortx8*)&sK[cur][((ks * 4 + quad) * 64 + ct * 16 + l16) * 8];
        s[ct] = mfma16(qf[ks], kf, s[ct]);
      }
    }

    // causal mask only on the diagonal tile (wave-uniform branch)
    if (kt == qt) {
      const int qrow = q0 + wave * 16 + quad * 4;
      #pragma unroll
      for (int ct = 0; ct < 4; ++ct) {
        const int kcol = kb + ct * 16 + l16;
        #pragma unroll
        for (int r = 0; r < 4; ++r)
          if (kcol > qrow + r) s[ct][r] = -__builtin_inff();
      }
    }

    // online softmax; scale folded into exp arg; per-lane partial l
    float alpha_r[4];
    #pragma unroll
    for (int r = 0; r < 4; ++r) {
      float mx = fmaxf(fmaxf(s[0][r], s[1][r]), fmaxf(s[2][r], s[3][r]));
      mx = fmaxf(mx, __shfl_xor(mx, 1));
      mx = fmaxf(mx, __shfl_xor(mx, 2));
      mx = fmaxf(mx, __shfl_xor(mx, 4));
      mx = fmaxf(mx, __shfl_xor(mx, 8));
      const float newm = fmaxf(m_i[r], mx);
      const float nmc = newm * cf;
      float p0 = exp2f(fmaf(s[0][r], cf, -nmc));
      float p1 = exp2f(fmaf(s[1][r], cf, -nmc));
      float p2 = exp2f(fmaf(s[2][r], cf, -nmc));
      float p3 = exp2f(fmaf(s[3][r], cf, -nmc));
      s[0][r] = p0; s[1][r] = p1; s[2][r] = p2; s[3][r] = p3;
      const float alpha = exp2f(fmaf(m_i[r], cf, -nmc));
      alpha_r[r] = alpha;
      l_i[r] = l_i[r] * alpha + ((p0 + p1) + (p2 + p3));
      m_i[r] = newm;
    }
    // rescale o_acc only if any lane's max moved (ballot-gated, wave-uniform)
    if (__ballot(alpha_r[0] < 1.f || alpha_r[1] < 1.f ||
                 alpha_r[2] < 1.f || alpha_r[3] < 1.f)) {
      #pragma unroll
      for (int nt = 0; nt < 8; ++nt)
        #pragma unroll
        for (int r = 0; r < 4; ++r) o_acc[nt][r] *= alpha_r[r];
    }

    // P: C-layout -> A-layout swizzled [k8][row][8], per-wave (no barrier)
    #pragma unroll
    for (int ct = 0; ct < 4; ++ct)
      #pragma unroll
      for (int r = 0; r < 4; ++r)
        sPw[((ct * 2 + (l16 >> 3)) * 16 + quad * 4 + r) * 8 + (l16 & 7)] = f2bf(s[ct][r]);
    __asm__ __volatile__("s_waitcnt lgkmcnt(0)" ::: "memory");

    // O += P V
    #pragma unroll
    for (int ks = 0; ks < 2; ++ks) {
      shortx8 pf = *(const shortx8*)&sPw[((ks * 4 + quad) * 16 + l16) * 8];
      #pragma unroll
      for (int nt = 0; nt < 8; ++nt) {
        shortx8 vf = *(const shortx8*)&sV[(nt * 16 + l16) * 72 + ks * 32 + quad * 8];
        o_acc[nt] = mfma16(pf, vf, o_acc[nt]);
      }
    }
  }

  const int trow = q0 + wave * 16 + quad * 4;
  #pragma unroll
  for (int r = 0; r < 4; ++r) {
    float l = l_i[r];
    l += __shfl_xor(l, 1);
    l += __shfl_xor(l, 2);
    l += __shfl_xor(l, 4);
    l += __shfl_xor(l, 8);
    const float inv = 1.f / l;
    #pragma unroll
    for (int nt = 0; nt < 8; ++nt) {
      aout[(size_t)(b * T_SEQ + trow + r) * D_MODEL + head * HEAD_DIM + nt * 16 + l16] =
          f2bf(o_acc[nt][r] * inv);
    }
  }
}

extern "C" void kernel_launch(void* const* d_in, const int* in_sizes, int n_in,
                              void* d_out, int out_size, void* d_ws, size_t ws_size,
                              hipStream_t stream) {
  const float* x      = (const float*)d_in[0];
  // d_in[1] = attn_mask (causal; unused)
  const float* qkv_w  = (const float*)d_in[2];
  const float* qkv_b  = (const float*)d_in[3];
  const float* proj_w = (const float*)d_in[4];
  const float* proj_b = (const float*)d_in[5];
  float* out = (float*)d_out;

  char* ws = (char*)d_ws;
  unsigned short* x_bf    = (unsigned short*)(ws);
  unsigned short* qkvw_t  = (unsigned short*)(ws + (size_t)16777216);
  unsigned short* projw_t = (unsigned short*)(ws + (size_t)29360128);
  unsigned short* qkvbuf  = (unsigned short*)(ws + (size_t)37748736);
  unsigned short* vtbuf   = (unsigned short*)(ws + (size_t)62914560);
  unsigned short* attn_out = x_bf;   // safe alias: x_bf dead after GEMM1

  cvt_x<<<(ROWS * D_MODEL / 4 + 255) / 256, 256, 0, stream>>>(x, x_bf, ROWS * D_MODEL / 4);
  transpose_cvt<<<dim3(QKV_N / 32, D_MODEL / 32), dim3(32, 8), 0, stream>>>(qkv_w, qkvw_t, D_MODEL, QKV_N);
  transpose_cvt<<<dim3(D_MODEL / 32, D_MODEL / 32), dim3(32, 8), 0, stream>>>(proj_w, projw_t, D_MODEL, D_MODEL);
  gemm_bt<<<dim3(QKV_N / 128, ROWS / 128), 256, 0, stream>>>(
      x_bf, qkvw_t, qkv_b, (void*)qkvbuf, ROWS, QKV_N, D_MODEL, 1);
  build_vt<<<dim3(T_SEQ / 32, 16, BATCH), dim3(32, 8), 0, stream>>>(qkvbuf, vtbuf);
  attn_kernel<<<dim3(T_SEQ / 64, N_HEADS, BATCH), 256, 0, stream>>>(qkvbuf, vtbuf, attn_out);
  gemm_bt<<<dim3(D_MODEL / 128, ROWS / 128), 256, 0, stream>>>(
      attn_out, projw_t, proj_b, (void*)out, ROWS, D_MODEL, D_MODEL, 0);
}

// Round 5
// 416.998 us; speedup vs baseline: 1.3093x; 1.3093x over previous
//
#include <hip/hip_runtime.h>
#include <cstdint>
#include <cstddef>

#define D_MODEL 2048
#define T_SEQ   2048
#define BATCH   2
#define N_HEADS 16
#define KV_HEADS 4
#define HEAD_DIM 128
#define QKV_N   3072          // D_MODEL + 2*512
#define ROWS    (BATCH * T_SEQ) // 4096

typedef float  floatx4 __attribute__((ext_vector_type(4)));
typedef short  shortx8 __attribute__((ext_vector_type(8)));
typedef __bf16 bf16x8  __attribute__((ext_vector_type(8)));

typedef const void __attribute__((address_space(1))) gvoid_t;
typedef void __attribute__((address_space(3)))       svoid_t;

__device__ __forceinline__ floatx4 mfma16(shortx8 a, shortx8 b, floatx4 c) {
  return __builtin_amdgcn_mfma_f32_16x16x32_bf16(
      __builtin_bit_cast(bf16x8, a), __builtin_bit_cast(bf16x8, b), c, 0, 0, 0);
}

__device__ __forceinline__ unsigned short f2bf(float f) {
  union { float f; unsigned int u; } v; v.f = f;
  unsigned int u = v.u;
  u += 0x7fffu + ((u >> 16) & 1u);   // RNE
  return (unsigned short)(u >> 16);
}

// ---------------- fp32 -> bf16 elementwise (x) ----------------
__global__ void cvt_x(const float* __restrict__ in, unsigned short* __restrict__ out, int n4) {
  int i = blockIdx.x * blockDim.x + threadIdx.x;
  if (i >= n4) return;
  float4 v = ((const float4*)in)[i];
  ushort4 o;
  o.x = f2bf(v.x); o.y = f2bf(v.y); o.z = f2bf(v.z); o.w = f2bf(v.w);
  ((ushort4*)out)[i] = o;
}

// ---------------- fp32 W[K][N] -> bf16 Wt[N][K] ----------------
__global__ void transpose_cvt(const float* __restrict__ W, unsigned short* __restrict__ Wt,
                              int K, int N) {
  __shared__ float tile[32][33];
  int n0 = blockIdx.x * 32, k0 = blockIdx.y * 32;
  int tx = threadIdx.x, ty = threadIdx.y;   // (32, 8)
  #pragma unroll
  for (int i = 0; i < 32; i += 8)
    tile[ty + i][tx] = W[(size_t)(k0 + ty + i) * N + n0 + tx];
  __syncthreads();
  #pragma unroll
  for (int i = 0; i < 32; i += 8)
    Wt[(size_t)(n0 + ty + i) * K + k0 + tx] = f2bf(tile[tx][ty + i]);
}

// ---------------- K slice of qkv -> k_staged [b][kvh][d8][t][8] ----------------
// writes fully coalesced (thread = output linear idx); reads are 16B gathers (L2/HBM-absorbed)
__global__ void build_kt(const unsigned short* __restrict__ qkv, unsigned short* __restrict__ kst) {
  int o = blockIdx.x * blockDim.x + threadIdx.x;   // (((b*4+kvh)*16+d8)*2048 + t)
  int t   = o & 2047;
  int d8  = (o >> 11) & 15;
  int kvh = (o >> 15) & 3;
  int b   = o >> 17;
  uint4 v = *(const uint4*)(qkv + (size_t)(b * T_SEQ + t) * QKV_N
                            + D_MODEL + kvh * HEAD_DIM + d8 * 8);
  *(uint4*)(kst + (size_t)o * 8) = v;
}

// ---------------- V slice of qkv -> v_staged [b][kvh][t8][d][8] ----------------
// writes coalesced; each of 8 reads per thread is lane-contiguous (2B x 64 lanes)
__global__ void build_vt(const unsigned short* __restrict__ qkv, unsigned short* __restrict__ vst) {
  int o = blockIdx.x * blockDim.x + threadIdx.x;   // (((b*4+kvh)*256+t8)*128 + d)
  int d   = o & 127;
  int t8  = (o >> 7) & 255;
  int kvh = (o >> 15) & 3;
  int b   = o >> 17;
  const unsigned short* src = qkv + (size_t)(b * T_SEQ + t8 * 8) * QKV_N
                              + D_MODEL + 512 + kvh * HEAD_DIM + d;
  union { unsigned short s[8]; uint4 v; } tmp;
  #pragma unroll
  for (int j = 0; j < 8; ++j) tmp.s[j] = src[(size_t)j * QKV_N];
  *(uint4*)(vst + (size_t)o * 8) = tmp.v;
}

// ---------------- bf16 GEMM: C[M][N] = A[M][K] * Bt[N][K]^T + bias ----------------
__global__ __launch_bounds__(256) void gemm_bt(
    const unsigned short* __restrict__ A,
    const unsigned short* __restrict__ Bt,
    const float* __restrict__ bias,
    void* __restrict__ Cout,
    int M, int N, int K, int c_bf16)
{
  __shared__ __align__(16) unsigned short sA[4 * 128 * 8];
  __shared__ __align__(16) unsigned short sB[4 * 128 * 8];
  const int tid  = threadIdx.x;
  const int wave = tid >> 6, lane = tid & 63;
  const int quad = lane >> 4, l16 = lane & 15;
  const int bm = blockIdx.y * 128, bn = blockIdx.x * 128;
  const int wm = (wave >> 1) * 64, wn = (wave & 1) * 64;
  floatx4 acc[4][4] = {};

  const int idx0 = tid, idx1 = 256 + tid;
  const int k8_0 = idx0 >> 7, r_0 = idx0 & 127;
  const int k8_1 = idx1 >> 7, r_1 = idx1 & 127;
  const unsigned short* a0 = A  + (size_t)(bm + r_0) * K + k8_0 * 8;
  const unsigned short* a1 = A  + (size_t)(bm + r_1) * K + k8_1 * 8;
  const unsigned short* b0 = Bt + (size_t)(bn + r_0) * K + k8_0 * 8;
  const unsigned short* b1 = Bt + (size_t)(bn + r_1) * K + k8_1 * 8;
  unsigned short* ldsA0 = &sA[(0 * 256 + wave * 64) * 8];
  unsigned short* ldsA1 = &sA[(1 * 256 + wave * 64) * 8];
  unsigned short* ldsB0 = &sB[(0 * 256 + wave * 64) * 8];
  unsigned short* ldsB1 = &sB[(1 * 256 + wave * 64) * 8];

  for (int k0 = 0; k0 < K; k0 += 32) {
    __syncthreads();
    __builtin_amdgcn_global_load_lds((gvoid_t*)(a0 + k0), (svoid_t*)ldsA0, 16, 0, 0);
    __builtin_amdgcn_global_load_lds((gvoid_t*)(a1 + k0), (svoid_t*)ldsA1, 16, 0, 0);
    __builtin_amdgcn_global_load_lds((gvoid_t*)(b0 + k0), (svoid_t*)ldsB0, 16, 0, 0);
    __builtin_amdgcn_global_load_lds((gvoid_t*)(b1 + k0), (svoid_t*)ldsB1, 16, 0, 0);
    __syncthreads();

    shortx8 af[4], bfq[4];
    #pragma unroll
    for (int mi = 0; mi < 4; ++mi)
      af[mi] = *(const shortx8*)&sA[(quad * 128 + wm + mi * 16 + l16) * 8];
    #pragma unroll
    for (int ni = 0; ni < 4; ++ni)
      bfq[ni] = *(const shortx8*)&sB[(quad * 128 + wn + ni * 16 + l16) * 8];
    #pragma unroll
    for (int mi = 0; mi < 4; ++mi)
      #pragma unroll
      for (int ni = 0; ni < 4; ++ni)
        acc[mi][ni] = mfma16(af[mi], bfq[ni], acc[mi][ni]);
  }

  #pragma unroll
  for (int mi = 0; mi < 4; ++mi) {
    #pragma unroll
    for (int ni = 0; ni < 4; ++ni) {
      const int row = bm + wm + mi * 16 + quad * 4;
      const int col = bn + wn + ni * 16 + l16;
      const float bv = bias[col];
      #pragma unroll
      for (int r = 0; r < 4; ++r) {
        float v = acc[mi][ni][r] + bv;
        if (c_bf16)
          ((unsigned short*)Cout)[(size_t)(row + r) * N + col] = f2bf(v);
        else
          ((float*)Cout)[(size_t)(row + r) * N + col] = v;
      }
    }
  }
}

// ---------------- flash attention, GQA, causal — uniform-cost blocks ----------------
// grid (16, N_HEADS, B) = 512 blocks, each processing the Q-tile PAIR
// (31 - bx, bx): cost = exactly 33 K-iterations per block -> zero tail,
// 2 blocks/CU resident for the whole kernel. Body = R3 structure:
// K/V staged via fully-coalesced global_load_lds from tile-linear k_staged/v_staged.
__global__ __launch_bounds__(256) void attn_kernel(
    const unsigned short* __restrict__ qkv,   // (B*T, 3072) bf16 (for Q)
    const unsigned short* __restrict__ kst,   // [b][kvh][d8][t][8]
    const unsigned short* __restrict__ vst,   // [b][kvh][t8][d][8]
    unsigned short* __restrict__ aout)        // (B*T, D_MODEL) bf16
{
  __shared__ __align__(16) unsigned short sK[16 * 64 * 8];   // [d8][key][8]
  __shared__ __align__(16) unsigned short sV[8 * 128 * 8];   // [t8][d][8]
  __shared__ __align__(16) unsigned short sP[4][8 * 16 * 8]; // per-wave [k8][row][8]

  const int tid  = threadIdx.x;
  const int wave = tid >> 6, lane = tid & 63;
  const int quad = lane >> 4, l16 = lane & 15;
  const int head = blockIdx.y, b = blockIdx.z;
  const int kvh = head >> 2;
  const float cf = 0.08838834764831845f * 1.4426950408889634f;  // scale*log2e

  const unsigned short* kbase = kst + (size_t)((b * KV_HEADS + kvh) * 16) * 2048 * 8;
  const unsigned short* vbase = vst + (size_t)((b * KV_HEADS + kvh) * 256) * 128 * 8;
  unsigned short* sPw = sP[wave];

  #pragma unroll 1
  for (int half = 0; half < 2; ++half) {
    const int qt = half ? blockIdx.x : (31 - blockIdx.x);
    const int q0 = qt * 64;

    // Q fragments straight to registers (A-layout: row=l16, k=ks*32+quad*8)
    shortx8 qf[4];
    {
      const unsigned short* qp = qkv + (size_t)(b * T_SEQ + q0 + wave * 16 + l16) * QKV_N
                                 + head * HEAD_DIM + quad * 8;
      #pragma unroll
      for (int ks = 0; ks < 4; ++ks)
        qf[ks] = *(const shortx8*)(qp + ks * 32);
    }

    float m_i[4], l_i[4];
    #pragma unroll
    for (int r = 0; r < 4; ++r) { m_i[r] = -__builtin_inff(); l_i[r] = 0.f; }
    floatx4 o_acc[8] = {};

    for (int kt = 0; kt <= qt; ++kt) {
      const int kb = kt * 64;

      __syncthreads();   // A: all waves done reading the previous tile
      // K tile: 16 chunks of 1KB, chunk c=[d8], lane=key -> fully coalesced
      #pragma unroll
      for (int it = 0; it < 4; ++it) {
        const int c = it * 4 + wave;
        __builtin_amdgcn_global_load_lds(
            (gvoid_t*)(kbase + ((size_t)c * 2048 + kb) * 8 + lane * 8),
            (svoid_t*)(sK + c * 512), 16, 0, 0);
      }
      // V tile: 16 chunks of 1KB, linear copy of v_staged -> fully coalesced
      const unsigned short* vtile = vbase + (size_t)(kb >> 3) * 128 * 8;
      #pragma unroll
      for (int it = 0; it < 4; ++it) {
        const int c = it * 4 + wave;
        __builtin_amdgcn_global_load_lds(
            (gvoid_t*)(vtile + c * 512 + lane * 8),
            (svoid_t*)(sV + c * 512), 16, 0, 0);
      }
      __syncthreads();   // B: tile visible (vmcnt drained by syncthreads)

      // S = Q K^T for this wave's 16 rows x 64 keys
      floatx4 s[4] = {};
      #pragma unroll
      for (int ks = 0; ks < 4; ++ks) {
        #pragma unroll
        for (int ct = 0; ct < 4; ++ct) {
          shortx8 kf = *(const shortx8*)&sK[((ks * 4 + quad) * 64 + ct * 16 + l16) * 8];
          s[ct] = mfma16(qf[ks], kf, s[ct]);
        }
      }

      // causal mask only on the diagonal tile (wave-uniform branch)
      if (kt == qt) {
        const int qrow = q0 + wave * 16 + quad * 4;
        #pragma unroll
        for (int ct = 0; ct < 4; ++ct) {
          const int kcol = kb + ct * 16 + l16;
          #pragma unroll
          for (int r = 0; r < 4; ++r)
            if (kcol > qrow + r) s[ct][r] = -__builtin_inff();
        }
      }

      // online softmax; scale folded into exp arg; per-lane partial l
      float alpha_r[4];
      #pragma unroll
      for (int r = 0; r < 4; ++r) {
        float mx = fmaxf(fmaxf(s[0][r], s[1][r]), fmaxf(s[2][r], s[3][r]));
        mx = fmaxf(mx, __shfl_xor(mx, 1));
        mx = fmaxf(mx, __shfl_xor(mx, 2));
        mx = fmaxf(mx, __shfl_xor(mx, 4));
        mx = fmaxf(mx, __shfl_xor(mx, 8));
        const float newm = fmaxf(m_i[r], mx);
        const float nmc = newm * cf;
        float p0 = exp2f(fmaf(s[0][r], cf, -nmc));
        float p1 = exp2f(fmaf(s[1][r], cf, -nmc));
        float p2 = exp2f(fmaf(s[2][r], cf, -nmc));
        float p3 = exp2f(fmaf(s[3][r], cf, -nmc));
        s[0][r] = p0; s[1][r] = p1; s[2][r] = p2; s[3][r] = p3;
        const float alpha = exp2f(fmaf(m_i[r], cf, -nmc));
        alpha_r[r] = alpha;
        l_i[r] = l_i[r] * alpha + ((p0 + p1) + (p2 + p3));
        m_i[r] = newm;
      }
      // rescale o_acc only if any lane's max moved (ballot-gated, wave-uniform)
      if (__ballot(alpha_r[0] < 1.f || alpha_r[1] < 1.f ||
                   alpha_r[2] < 1.f || alpha_r[3] < 1.f)) {
        #pragma unroll
        for (int nt = 0; nt < 8; ++nt)
          #pragma unroll
          for (int r = 0; r < 4; ++r) o_acc[nt][r] *= alpha_r[r];
      }

      // P: C-layout -> A-layout swizzled [k8][row][8], per-wave (no barrier)
      #pragma unroll
      for (int ct = 0; ct < 4; ++ct)
        #pragma unroll
        for (int r = 0; r < 4; ++r)
          sPw[((ct * 2 + (l16 >> 3)) * 16 + quad * 4 + r) * 8 + (l16 & 7)] = f2bf(s[ct][r]);
      __asm__ __volatile__("s_waitcnt lgkmcnt(0)" ::: "memory");

      // O += P V
      #pragma unroll
      for (int ks = 0; ks < 2; ++ks) {
        shortx8 pf = *(const shortx8*)&sPw[((ks * 4 + quad) * 16 + l16) * 8];
        #pragma unroll
        for (int nt = 0; nt < 8; ++nt) {
          shortx8 vf = *(const shortx8*)&sV[((ks * 4 + quad) * 128 + nt * 16 + l16) * 8];
          o_acc[nt] = mfma16(pf, vf, o_acc[nt]);
        }
      }
    }

    // epilogue for this q-tile
    const int trow = q0 + wave * 16 + quad * 4;
    #pragma unroll
    for (int r = 0; r < 4; ++r) {
      float l = l_i[r];
      l += __shfl_xor(l, 1);
      l += __shfl_xor(l, 2);
      l += __shfl_xor(l, 4);
      l += __shfl_xor(l, 8);
      const float inv = 1.f / l;
      #pragma unroll
      for (int nt = 0; nt < 8; ++nt) {
        aout[(size_t)(b * T_SEQ + trow + r) * D_MODEL + head * HEAD_DIM + nt * 16 + l16] =
            f2bf(o_acc[nt][r] * inv);
      }
    }
  }
}

extern "C" void kernel_launch(void* const* d_in, const int* in_sizes, int n_in,
                              void* d_out, int out_size, void* d_ws, size_t ws_size,
                              hipStream_t stream) {
  const float* x      = (const float*)d_in[0];
  // d_in[1] = attn_mask (causal; unused)
  const float* qkv_w  = (const float*)d_in[2];
  const float* qkv_b  = (const float*)d_in[3];
  const float* proj_w = (const float*)d_in[4];
  const float* proj_b = (const float*)d_in[5];
  float* out = (float*)d_out;

  char* ws = (char*)d_ws;
  // layout (bytes):
  //   [0,16M)    x_bf16, later aliased as attn_out (x_bf dead after GEMM1)
  //   [16M,28M)  qkvw_t, later aliased: k_staged [16M,20M) (qkvw_t dead after GEMM1)
  //   [28M,36M)  projw_t
  //   [36M,60M)  qkv_bf16
  //   [60M,64M)  v_staged
  unsigned short* x_bf    = (unsigned short*)(ws);
  unsigned short* qkvw_t  = (unsigned short*)(ws + (size_t)16777216);
  unsigned short* projw_t = (unsigned short*)(ws + (size_t)29360128);
  unsigned short* qkvbuf  = (unsigned short*)(ws + (size_t)37748736);
  unsigned short* vstaged = (unsigned short*)(ws + (size_t)62914560);
  unsigned short* kstaged = qkvw_t;  // safe alias: qkvw_t dead after GEMM1
  unsigned short* attn_out = x_bf;   // safe alias: x_bf dead after GEMM1

  cvt_x<<<(ROWS * D_MODEL / 4 + 255) / 256, 256, 0, stream>>>(x, x_bf, ROWS * D_MODEL / 4);
  transpose_cvt<<<dim3(QKV_N / 32, D_MODEL / 32), dim3(32, 8), 0, stream>>>(qkv_w, qkvw_t, D_MODEL, QKV_N);
  transpose_cvt<<<dim3(D_MODEL / 32, D_MODEL / 32), dim3(32, 8), 0, stream>>>(proj_w, projw_t, D_MODEL, D_MODEL);
  gemm_bt<<<dim3(QKV_N / 128, ROWS / 128), 256, 0, stream>>>(
      x_bf, qkvw_t, qkv_b, (void*)qkvbuf, ROWS, QKV_N, D_MODEL, 1);
  build_kt<<<1024, 256, 0, stream>>>(qkvbuf, kstaged);
  build_vt<<<1024, 256, 0, stream>>>(qkvbuf, vstaged);
  attn_kernel<<<dim3(16, N_HEADS, BATCH), 256, 0, stream>>>(qkvbuf, kstaged, vstaged, attn_out);
  gemm_bt<<<dim3(D_MODEL / 128, ROWS / 128), 256, 0, stream>>>(
      attn_out, projw_t, proj_b, (void*)out, ROWS, D_MODEL, D_MODEL, 0);
}